// Round 3
// baseline (826.655 us; speedup 1.0000x reference)
//
#include <hip/hip_runtime.h>
#include <hip/hip_bf16.h>
#include <stdint.h>

typedef __attribute__((ext_vector_type(4))) float f32x4;
typedef __attribute__((ext_vector_type(8))) short s16x8;
typedef unsigned short u16;

#define BM 256
#define BN 256
#define BK 64

// round-to-nearest-even f32 -> bf16 (bit pattern)
__device__ __forceinline__ u16 f32_to_bf16(float f) {
    uint32_t u = __float_as_uint(f);
    u = u + 0x7FFFu + ((u >> 16) & 1u);
    return (u16)(u >> 16);
}

__device__ __forceinline__ void gld_lds16(const void* g, void* l) {
    __builtin_amdgcn_global_load_lds(
        (const __attribute__((address_space(1))) uint32_t*)g,
        (__attribute__((address_space(3))) uint32_t*)l,
        16, 0, 0);
}

// Transpose + convert: out[c*R + r] = bf16(in[r*C + c]).  R, C multiples of 32.
__global__ void stein_transpose_f32_bf16(const float* __restrict__ in,
                                         u16* __restrict__ out, int R, int C) {
    __shared__ float tile[32][33];
    const int tx = threadIdx.x, ty = threadIdx.y;     // 32 x 8
    const int c0 = blockIdx.x * 32, r0 = blockIdx.y * 32;
#pragma unroll
    for (int i = 0; i < 32; i += 8)
        tile[ty + i][tx] = in[(size_t)(r0 + ty + i) * C + (c0 + tx)];
    __syncthreads();
#pragma unroll
    for (int i = 0; i < 32; i += 8)
        out[(size_t)(c0 + ty + i) * R + (r0 + tx)] = f32_to_bf16(tile[tx][ty + i]);
}

// Straight convert f32 -> bf16, 4 elements/thread. n multiple of 4.
__global__ void stein_convert_f32_bf16(const float* __restrict__ in,
                                       u16* __restrict__ out, int n) {
    int i = (blockIdx.x * blockDim.x + threadIdx.x) * 4;
    if (i >= n) return;
    f32x4 v = *(const f32x4*)(in + i);
    uint2 u;
    u.x = (uint32_t)f32_to_bf16(v[0]) | ((uint32_t)f32_to_bf16(v[1]) << 16);
    u.y = (uint32_t)f32_to_bf16(v[2]) | ((uint32_t)f32_to_bf16(v[3]) << 16);
    *(uint2*)(out + i) = u;
}

// Runtime-descriptor GEMM op: C[m,n] = sum_k U[m,k] V[n,k]  (NT, bf16 in).
struct GemmOp {
    const u16* U; const u16* V;
    const float* Add;
    u16* OutB; u16* OutT; float* OutF;
    int K, ldu, ldv, N, ldo;
};

// R15: m201-port. 256x256x64 tile, 8 waves (2Mx4N, wave-tile 128x64).
// LDS model: per K-tile, ds_read 192 KB + gld-write 64 KB = 1000 cyc at
// 256 B/cyc vs 614 cyc MFMA -> 61% MfmaUtil ceiling (128-tile structures
// cap at 41-45%, which is the real "m97 ~900 TF wall"). 128 KiB LDS
// double-buffer [buf][half(128rows)]. 4 phases per K-tile, each:
// {ds_read subtile, stage 1 half-tile of t+1, barrier, lgkmcnt(0),
// setprio 16-MFMA quadrant, barrier}. Reads distributed {12,4,8,0} so the
// whole tile's LDS is dead after P2's barrier -> P3 stages A-h0(t+2) into
// the CURRENT buffer, making the boundary wait a counted vmcnt(2)
// (2 loads stay in flight across every tile boundary; vmcnt(0) only at
// the tail). vmcnt scheme is spill-robust: completion is oldest-first and
// needed halves are always older than the 2-op allowance.
// Quadrants: P0(i0-3,j0-1) P1(i0-3,j2-3) P2(i4-7,j2-3) P3(i4-7,j0-1);
// per-acc K-order identical to R12 -> numerics unchanged.
// Regs: 128 acc(AGPR) + 64 frag VGPR + addr ~30 <= 256 -> 2 waves/SIMD.
// Bank swizzle (0 conflicts measured): physical chunk p of row r holds
// logical chunk p ^ (r&7); readers use (s*4+(lane>>4)) ^ (lane&7).
// grid (8,8,z): 64 blocks/op, 1 block/CU (128 KiB LDS).
__global__ __launch_bounds__(512, 2) void stein_gemm_nt2(GemmOp op0, GemmOp op1,
                                                         GemmOp op2, GemmOp op3,
                                                         GemmOp op4) {
    const int z = blockIdx.z;
    const GemmOp op = (z == 0) ? op0 : (z == 1) ? op1 : (z == 2) ? op2
                      : (z == 3) ? op3 : op4;
    const int bm = blockIdx.x, bn = blockIdx.y;
    if (bn * BN >= op.N) return;              // rectangular (N=512) ops

    __shared__ alignas(16) short As[2][2][128 * 64];   // [buf][half] 64 KB
    __shared__ alignas(16) short Bs[2][2][128 * 64];   // [buf][half] 64 KB

    const int tid = threadIdx.x;
    const int wave = tid >> 6;
    const int lane = tid & 63;
    const int wr = wave >> 2;                 // 0..1: A half (M)
    const int wc = wave & 3;                  // 0..3: N quarter

    // staging: each wave covers rows [16w,16w+16) of every half; 2 issues
    // of 8 rows x 128 B.
    const int lrow8 = lane >> 3;                  // 0..7
    const int lchunk = (lane & 7) ^ lrow8;        // swizzled source chunk
    const u16* gU = op.U + (size_t)(bm * BM + 16 * wave + lrow8) * op.ldu + lchunk * 8;
    const u16* gV = op.V + (size_t)(bn * BN + 16 * wave + lrow8) * op.ldv + lchunk * 8;
    const int so = (16 * wave) * 64;              // shorts, within one half

#define STAGE_A(T, h, bsel) do { \
    gld_lds16(gU + (size_t)((h) * 128) * op.ldu + (size_t)(T) * 64, &As[bsel][h][so]); \
    gld_lds16(gU + (size_t)((h) * 128 + 8) * op.ldu + (size_t)(T) * 64, &As[bsel][h][so + 512]); \
} while (0)
#define STAGE_B(T, h, bsel) do { \
    gld_lds16(gV + (size_t)((h) * 128) * op.ldv + (size_t)(T) * 64, &Bs[bsel][h][so]); \
    gld_lds16(gV + (size_t)((h) * 128 + 8) * op.ldv + (size_t)(T) * 64, &Bs[bsel][h][so + 512]); \
} while (0)

    f32x4 acc[8][4];
#pragma unroll
    for (int i = 0; i < 8; ++i)
#pragma unroll
        for (int j = 0; j < 4; ++j) acc[i][j] = (f32x4){0.f, 0.f, 0.f, 0.f};

    const int l15 = lane & 15;
    const int brl = (wc & 1) * 64;                   // B local row base
    const int cx0 = (lane >> 4) ^ (lane & 7);        // phys chunk, k-step 0
    const int cx1 = (4 | (lane >> 4)) ^ (lane & 7);  // phys chunk, k-step 1

    const int NT = op.K / BK;                 // >= 8 for all ops here

    // prologue: tile 0 fully + A-h0 of tile 1; 2 loads stay in flight.
    STAGE_A(0, 0, 0); STAGE_A(0, 1, 0); STAGE_B(0, 0, 0); STAGE_B(0, 1, 0);
    STAGE_A(1, 0, 1);
    asm volatile("s_waitcnt vmcnt(2)" ::: "memory");
    __builtin_amdgcn_s_barrier();
    asm volatile("" ::: "memory");

    for (int t = 0; t < NT; ++t) {
        const int p = t & 1, q2 = p ^ 1;
        const bool s1 = (t + 1) < NT;
        const bool s2 = (t + 2) < NT;
        const s16x8* ApL = (const s16x8*)&As[p][wr][0];
        const s16x8* BpL = (const s16x8*)&Bs[p][wc >> 1][0];

        s16x8 a[8][2], b[4][2];

        // ---- P0: reads {a0-3, b0-1}; MFMA quadrant (i0-3, j0-1) ----
#pragma unroll
        for (int i = 0; i < 4; ++i) {
            a[i][0] = ApL[(i * 16 + l15) * 8 + cx0];
            a[i][1] = ApL[(i * 16 + l15) * 8 + cx1];
        }
#pragma unroll
        for (int j = 0; j < 2; ++j) {
            b[j][0] = BpL[(brl + j * 16 + l15) * 8 + cx0];
            b[j][1] = BpL[(brl + j * 16 + l15) * 8 + cx1];
        }
        if (s1) STAGE_A(t + 1, 1, q2);
        asm volatile("" ::: "memory");
        __builtin_amdgcn_s_barrier();
        asm volatile("s_waitcnt lgkmcnt(0)" ::: "memory");
        __builtin_amdgcn_sched_barrier(0);
        __builtin_amdgcn_s_setprio(1);
#pragma unroll
        for (int i = 0; i < 4; ++i)
#pragma unroll
            for (int j = 0; j < 2; ++j) {
                acc[i][j] = __builtin_amdgcn_mfma_f32_16x16x32_bf16(
                    a[i][0], b[j][0], acc[i][j], 0, 0, 0);
                acc[i][j] = __builtin_amdgcn_mfma_f32_16x16x32_bf16(
                    a[i][1], b[j][1], acc[i][j], 0, 0, 0);
            }
        __builtin_amdgcn_s_setprio(0);
        asm volatile("" ::: "memory");
        __builtin_amdgcn_s_barrier();
        asm volatile("" ::: "memory");

        // ---- P1: reads {b2-3}; MFMA quadrant (i0-3, j2-3) ----
#pragma unroll
        for (int j = 0; j < 2; ++j) {
            b[2 + j][0] = BpL[(brl + (2 + j) * 16 + l15) * 8 + cx0];
            b[2 + j][1] = BpL[(brl + (2 + j) * 16 + l15) * 8 + cx1];
        }
        if (s1) STAGE_B(t + 1, 0, q2);
        asm volatile("" ::: "memory");
        __builtin_amdgcn_s_barrier();
        asm volatile("s_waitcnt lgkmcnt(0)" ::: "memory");
        __builtin_amdgcn_sched_barrier(0);
        __builtin_amdgcn_s_setprio(1);
#pragma unroll
        for (int i = 0; i < 4; ++i)
#pragma unroll
            for (int j = 0; j < 2; ++j) {
                acc[i][2 + j] = __builtin_amdgcn_mfma_f32_16x16x32_bf16(
                    a[i][0], b[2 + j][0], acc[i][2 + j], 0, 0, 0);
                acc[i][2 + j] = __builtin_amdgcn_mfma_f32_16x16x32_bf16(
                    a[i][1], b[2 + j][1], acc[i][2 + j], 0, 0, 0);
            }
        __builtin_amdgcn_s_setprio(0);
        asm volatile("" ::: "memory");
        __builtin_amdgcn_s_barrier();
        asm volatile("" ::: "memory");

        // ---- P2: reads {a4-7}; MFMA quadrant (i4-7, j2-3) ----
#pragma unroll
        for (int i = 0; i < 4; ++i) {
            a[4 + i][0] = ApL[((4 + i) * 16 + l15) * 8 + cx0];
            a[4 + i][1] = ApL[((4 + i) * 16 + l15) * 8 + cx1];
        }
        if (s1) STAGE_B(t + 1, 1, q2);
        asm volatile("" ::: "memory");
        __builtin_amdgcn_s_barrier();
        asm volatile("s_waitcnt lgkmcnt(0)" ::: "memory");
        __builtin_amdgcn_sched_barrier(0);
        __builtin_amdgcn_s_setprio(1);
#pragma unroll
        for (int i = 0; i < 4; ++i)
#pragma unroll
            for (int j = 0; j < 2; ++j) {
                acc[4 + i][2 + j] = __builtin_amdgcn_mfma_f32_16x16x32_bf16(
                    a[4 + i][0], b[2 + j][0], acc[4 + i][2 + j], 0, 0, 0);
                acc[4 + i][2 + j] = __builtin_amdgcn_mfma_f32_16x16x32_bf16(
                    a[4 + i][1], b[2 + j][1], acc[4 + i][2 + j], 0, 0, 0);
            }
        __builtin_amdgcn_s_setprio(0);
        asm volatile("" ::: "memory");
        __builtin_amdgcn_s_barrier();
        asm volatile("" ::: "memory");

        // ---- P3: no reads (tile LDS dead since P2 barrier) ----
        // stage A-h0(t+2) into the CURRENT buffer -> boundary wait stays
        // counted (vmcnt(2)), loads span the tile boundary.
        if (s2) STAGE_A(t + 2, 0, p);
        asm volatile("" ::: "memory");
        __builtin_amdgcn_s_barrier();
        asm volatile("" ::: "memory");
        __builtin_amdgcn_s_setprio(1);
#pragma unroll
        for (int i = 0; i < 4; ++i)
#pragma unroll
            for (int j = 0; j < 2; ++j) {
                acc[4 + i][j] = __builtin_amdgcn_mfma_f32_16x16x32_bf16(
                    a[4 + i][0], b[j][0], acc[4 + i][j], 0, 0, 0);
                acc[4 + i][j] = __builtin_amdgcn_mfma_f32_16x16x32_bf16(
                    a[4 + i][1], b[j][1], acc[4 + i][j], 0, 0, 0);
            }
        __builtin_amdgcn_s_setprio(0);
        if (s2) {
            asm volatile("s_waitcnt vmcnt(2)" ::: "memory");   // tile t+1 landed
        } else if (s1) {
            asm volatile("s_waitcnt vmcnt(0)" ::: "memory");   // tail drain
        }
        asm volatile("" ::: "memory");
        __builtin_amdgcn_s_barrier();
        asm volatile("" ::: "memory");
    }
#undef STAGE_A
#undef STAGE_B

    // ---- epilogue ----  C/D layout: col=lane&15, row=(lane>>4)*4+r
    const int ldo = op.ldo;
    const int ccol = lane & 15;
    const int crow = (lane >> 4) * 4;
#pragma unroll
    for (int i = 0; i < 8; ++i) {
#pragma unroll
        for (int j = 0; j < 4; ++j) {
            const int gr0 = bm * BM + wr * 128 + i * 16 + crow;
            const int gc = bn * BN + wc * 64 + j * 16 + ccol;
            float v[4];
#pragma unroll
            for (int r = 0; r < 4; ++r) {
                v[r] = acc[i][j][r];
                if (op.Add) v[r] += op.Add[(size_t)(gr0 + r) * ldo + gc];
            }
            if (op.OutB) {
#pragma unroll
                for (int r = 0; r < 4; ++r)
                    op.OutB[(size_t)(gr0 + r) * ldo + gc] = f32_to_bf16(v[r]);
            }
            if (op.OutT) {
                uint2 u;
                u.x = (uint32_t)f32_to_bf16(v[0]) | ((uint32_t)f32_to_bf16(v[1]) << 16);
                u.y = (uint32_t)f32_to_bf16(v[2]) | ((uint32_t)f32_to_bf16(v[3]) << 16);
                *(uint2*)(&op.OutT[(size_t)gc * ldo + gr0]) = u;   // gr0 % 4 == 0
            }
            if (op.OutF) {
#pragma unroll
                for (int r = 0; r < 4; ++r)
                    op.OutF[(size_t)(gr0 + r) * ldo + gc] = v[r];
            }
        }
    }
}

static inline GemmOp mkop(const u16* U, const u16* V, int K, int ldu, int ldv,
                          const float* Add, u16* OutB, u16* OutT, float* OutF,
                          int N = 2048, int ldo = 2048) {
    GemmOp o;
    o.U = U; o.V = V; o.Add = Add; o.OutB = OutB; o.OutT = OutT; o.OutF = OutF;
    o.K = K; o.ldu = ldu; o.ldv = ldv; o.N = N; o.ldo = ldo;
    return o;
}

extern "C" void kernel_launch(void* const* d_in, const int* in_sizes, int n_in,
                              void* d_out, int out_size, void* d_ws, size_t ws_size,
                              hipStream_t stream) {
    const float* A = (const float*)d_in[0];     // (2048, 2048)
    const float* A_F = (const float*)d_in[1];   // (2048, 2048)
    const float* C = (const float*)d_in[2];     // (512, 2048)
    const float* C_F = (const float*)d_in[3];   // (512, 2048)
    const int n = 2048, p = 512;
    (void)in_sizes; (void)n_in; (void)out_size; (void)ws_size;

    char* ws = (char*)d_ws;
    const size_t MB = 1u << 20;
    // ---- Smith squaring, 5 levels -> S_32.
    // Tail bound: sigma_max(A),(B) ~ 0.909 (Ginibre 2*sqrt(n)*s), so
    // |S_50 - S_32| <= 20*0.909^64/0.174 ~ 0.25 absmax (<=0.62 at sigma=0.92);
    // + bf16 path 0.5 -> ~1.1 total, under the 2.33 threshold.
    // Level 0 rank-512: B R_0 A = (B C_F^T)(C A)^T = W1 Y^T (0.75 GEMM-units).
    u16* AT   = (u16*)(ws + 0 * MB);    // A^T  bf16  (A_0 transposed form)
    u16* Ab   = (u16*)(ws + 8 * MB);    // A    bf16  (A_0 row form)
    u16* AFT  = (u16*)(ws + 16 * MB);   // B=A_F^T row bf16 (B_0 row form)
    u16* AFb  = (u16*)(ws + 24 * MB);   // A_F  bf16  (B_0 transposed form)
    u16* CFT  = (u16*)(ws + 32 * MB);   // C_F^T bf16 (2048x512)
    u16* CT   = (u16*)(ws + 34 * MB);   // C^T   bf16 (2048x512)
    float* R32 = (float*)(ws + 36 * MB);// running R fp32
    u16* Rb   = (u16*)(ws + 52 * MB);   // running R bf16 row
    u16* XT   = (u16*)(ws + 60 * MB);   // (R*A_i)^T bf16 — used from level 1 on
    u16* W1b  = (u16*)(ws + 60 * MB);   // W1 = B C_F^T bf16 (2048x512, level 0 only)
    u16* Yb   = (u16*)(ws + 62 * MB);   // Y = A^T C^T bf16 (2048x512, level 0 only)
    u16* CFb  = (u16*)(ws + 64 * MB);   // C_F bf16 row (512x2048, level 0 only)
    u16* Cb   = (u16*)(ws + 66 * MB);   // C   bf16 row (512x2048, level 0 only)
    u16* Tb1  = (u16*)(ws + 68 * MB);   // ping-pong set 1: B_i row
    u16* TbT1 = (u16*)(ws + 76 * MB);   //                  B_i^T
    u16* Ub1  = (u16*)(ws + 84 * MB);   //                  A_i row
    u16* UbT1 = (u16*)(ws + 92 * MB);   //                  A_i^T

    dim3 tb(32, 8);
    stein_transpose_f32_bf16<<<dim3(64, 64), tb, 0, stream>>>(A, AT, n, n);
    stein_convert_f32_bf16<<<4096, 256, 0, stream>>>(A, Ab, n * n);
    stein_transpose_f32_bf16<<<dim3(64, 64), tb, 0, stream>>>(A_F, AFT, n, n);
    stein_convert_f32_bf16<<<4096, 256, 0, stream>>>(A_F, AFb, n * n);
    stein_transpose_f32_bf16<<<dim3(64, 16), tb, 0, stream>>>(C_F, CFT, p, n);
    stein_transpose_f32_bf16<<<dim3(64, 16), tb, 0, stream>>>(C, CT, p, n);
    stein_convert_f32_bf16<<<1024, 256, 0, stream>>>(C_F, CFb, p * n);
    stein_convert_f32_bf16<<<1024, 256, 0, stream>>>(C, Cb, p * n);

    u16* Tb[2]  = {AFT, Tb1};
    u16* TbT[2] = {AFb, TbT1};
    u16* Ub[2]  = {Ab, Ub1};
    u16* UbT[2] = {AT, UbT1};

    dim3 blk(512);
    dim3 g1(8, 8, 1), g2(8, 8, 2), g5(8, 8, 5);

    // d0 (z=5): level-0 independent ops. R12: long K=2048 ops at low z so
    // stragglers are the short K=512 R0 blocks.
    {
        GemmOp oW1  = mkop(AFT, CFb, n, n, n, nullptr, W1b, nullptr, nullptr, p, p);
        GemmOp oY   = mkop(AT, Cb, n, n, n, nullptr, Yb, nullptr, nullptr, p, p);
        GemmOp oAsq = mkop(Ub[0], UbT[0], n, n, n, nullptr, Ub[1], UbT[1], nullptr);
        GemmOp oBsq = mkop(Tb[0], TbT[0], n, n, n, nullptr, Tb[1], TbT[1], nullptr);
        GemmOp oR0  = mkop(CFT, CT, p, p, p, nullptr, nullptr, nullptr, R32);
        stein_gemm_nt2<<<g5, blk, 0, stream>>>(oW1, oY, oAsq, oBsq, oR0);
    }
    // d0b: R_1 = W1 Y^T + R_0  (K=512)
    {
        GemmOp oRup = mkop(W1b, Yb, p, p, p, R32, Rb, nullptr, R32);
        stein_gemm_nt2<<<g1, blk, 0, stream>>>(oRup, oRup, oRup, oRup, oRup);
    }

    // levels 1..3: full doubling, R10 stream-sharing pairing.
    // R_j = S_{2^j}; after level 3: R_4 = S_16, A_4 = A^16 in set 0.
    for (int i = 1; i < 4; ++i) {
        const int c = i & 1, nx = c ^ 1;
        GemmOp oXT = mkop(Rb, UbT[c], n, n, n, nullptr, nullptr, XT, nullptr);
        // d1: {XT = R A_i, Asq = A_i^2} — shared V stream = A_i^T.
        GemmOp oAsq = mkop(Ub[c], UbT[c], n, n, n, nullptr, Ub[nx], UbT[nx], nullptr);
        stein_gemm_nt2<<<g2, blk, 0, stream>>>(oXT, oAsq, oAsq, oAsq, oAsq);
        // d2: {Rup = B_i X + R, Bsq = B_i^2} — shared U stream = B_i.
        GemmOp oRup = mkop(Tb[c], XT, n, n, n, R32, Rb, nullptr, R32);
        GemmOp oBsq = mkop(Tb[c], TbT[c], n, n, n, nullptr, Tb[nx], TbT[nx], nullptr);
        stein_gemm_nt2<<<g2, blk, 0, stream>>>(oRup, oBsq, oBsq, oBsq, oBsq);
    }

    // level 4 (final): S_32 = R_4 + B_4 (R_4 A_4) -> d_out. A_4/B_4 in set 0.
    {
        const int c = 0;
        GemmOp oXT = mkop(Rb, UbT[c], n, n, n, nullptr, nullptr, XT, nullptr);
        stein_gemm_nt2<<<g1, blk, 0, stream>>>(oXT, oXT, oXT, oXT, oXT);
        GemmOp oFin = mkop(Tb[c], XT, n, n, n, R32, nullptr, nullptr, (float*)d_out);
        stein_gemm_nt2<<<g1, blk, 0, stream>>>(oFin, oFin, oFin, oFin, oFin);
    }
}

// Round 4
// 637.939 us; speedup vs baseline: 1.2958x; 1.2958x over previous
//
#include <hip/hip_runtime.h>
#include <hip/hip_bf16.h>
#include <stdint.h>

typedef __attribute__((ext_vector_type(4))) float f32x4;
typedef __attribute__((ext_vector_type(8))) short s16x8;
typedef unsigned short u16;

#define BM 256
#define BN 128
#define BK 64

// round-to-nearest-even f32 -> bf16 (bit pattern)
__device__ __forceinline__ u16 f32_to_bf16(float f) {
    uint32_t u = __float_as_uint(f);
    u = u + 0x7FFFu + ((u >> 16) & 1u);
    return (u16)(u >> 16);
}

__device__ __forceinline__ void gld_lds16(const void* g, void* l) {
    __builtin_amdgcn_global_load_lds(
        (const __attribute__((address_space(1))) uint32_t*)g,
        (__attribute__((address_space(3))) uint32_t*)l,
        16, 0, 0);
}

// Transpose + convert: out[c*R + r] = bf16(in[r*C + c]).  R, C multiples of 32.
__global__ void stein_transpose_f32_bf16(const float* __restrict__ in,
                                         u16* __restrict__ out, int R, int C) {
    __shared__ float tile[32][33];
    const int tx = threadIdx.x, ty = threadIdx.y;     // 32 x 8
    const int c0 = blockIdx.x * 32, r0 = blockIdx.y * 32;
#pragma unroll
    for (int i = 0; i < 32; i += 8)
        tile[ty + i][tx] = in[(size_t)(r0 + ty + i) * C + (c0 + tx)];
    __syncthreads();
#pragma unroll
    for (int i = 0; i < 32; i += 8)
        out[(size_t)(c0 + ty + i) * R + (r0 + tx)] = f32_to_bf16(tile[tx][ty + i]);
}

// Straight convert f32 -> bf16, 4 elements/thread. n multiple of 4.
__global__ void stein_convert_f32_bf16(const float* __restrict__ in,
                                       u16* __restrict__ out, int n) {
    int i = (blockIdx.x * blockDim.x + threadIdx.x) * 4;
    if (i >= n) return;
    f32x4 v = *(const f32x4*)(in + i);
    uint2 u;
    u.x = (uint32_t)f32_to_bf16(v[0]) | ((uint32_t)f32_to_bf16(v[1]) << 16);
    u.y = (uint32_t)f32_to_bf16(v[2]) | ((uint32_t)f32_to_bf16(v[3]) << 16);
    *(uint2*)(out + i) = u;
}

// Runtime-descriptor GEMM op: C[m,n] = sum_k U[m,k] V[n,k]  (NT, bf16 in).
struct GemmOp {
    const u16* U; const u16* V;
    const float* Add;
    u16* OutB; u16* OutT; float* OutF;
    int K, ldu, ldv, N, ldo;
};

// R16: deadline-staged 4-phase schedule, 256x128x64 tile, 8 waves (4Mx2N,
// 64x64/wave). grid (8,16,z) -> 128 blocks/op; 2-op rounds = 256 = full
// machine at 1 block/CU (LDS 96 KiB dbuf). R15 lessons: (a) 256^2 tile
// starves the grid at N=2048; (b) boundary vmcnt must certify stages
// issued SEVERAL phases ago (R15's 1-phase cover stalled every tile).
// Staging decomposed into 6 deadline-tagged 8-row units/wave/tile:
//   [B-Lo, A-Lo0] @P0, [A-Lo1, B-Hi] @P1, [A-Hi0, A-Hi1] @P2, none @P3
// consumed (as ds_reads) at: A-Lo P0, B-Hi P1, A-Hi P2, B-Lo P3(pre-read
// for t+1) -> every unit has 2-4 phases of issue->certify cover. Phase-end
// counted waits: vmcnt{4,4,5,3} (never 0 in main loop; 0 only last tile).
// Per phase: {4 ds_read_b128, 2 stage units, vmcnt, BAR, lgkmcnt(0),
// setprio(1) 8-MFMA quadrant setprio(0), BAR}. Reads balanced {4,4,4,4}.
// b-lo of tile t+1 pre-read in P3 into ping-pong regs (static indexing,
// 2-tile unrolled loop). Safety: all CB reads drained by P2's lgkmcnt+BAR,
// 3 barriers before any restage into CB; NB pre-reads certified by P2-end
// vmcnt(5)+BAR. Per-acc K accumulation order identical to R12.
// Bank swizzle (0 conflicts measured): physical chunk p of row r holds
// logical chunk p ^ (r&7); readers use (s*4+(lane>>4)) ^ (lane&7).
__global__ __launch_bounds__(512, 2) void stein_gemm_nt2(GemmOp op0, GemmOp op1,
                                                         GemmOp op2, GemmOp op3,
                                                         GemmOp op4) {
    const int z = blockIdx.z;
    const GemmOp op = (z == 0) ? op0 : (z == 1) ? op1 : (z == 2) ? op2
                      : (z == 3) ? op3 : op4;
    const int bm = blockIdx.x, bn = blockIdx.y;
    if (bn * BN >= op.N) return;              // rectangular (N=512) ops

    __shared__ alignas(16) short As[2][BM * BK];   // 2 x 32 KB
    __shared__ alignas(16) short Bs[2][BN * BK];   // 2 x 16 KB

    const int tid = threadIdx.x;
    const int wave = tid >> 6;
    const int lane = tid & 63;
    const int wm = (wave >> 1) * 64;          // 4 M-groups of 64 rows
    const int wn = (wave & 1) * 64;           // 2 N-groups of 64 cols

    const int lrow8 = lane >> 3;                  // 0..7
    const int lchunk = (lane & 7) ^ lrow8;        // swizzled source chunk
    const u16* gU = op.U + (size_t)(bm * BM + lrow8) * op.ldu + lchunk * 8;
    const u16* gV = op.V + (size_t)(bn * BN + lrow8) * op.ldv + lchunk * 8;

    // deadline-stage units (8 rows each). A-Lo = rows (g*64)+0..31 over the
    // 4 M-strips; wave stages A-Lo units {2w,2w+1}, A-Hi same +32; B-Lo
    // unit w of the 2 N-strips, B-Hi +32. rowOf(u) = (u>>2)*64 + (u&3)*8.
    const int uA0 = 2 * wave, uA1 = 2 * wave + 1;
    const int rAL0 = (uA0 >> 2) * 64 + (uA0 & 3) * 8;
    const int rAL1 = (uA1 >> 2) * 64 + (uA1 & 3) * 8;
    const int rAH0 = rAL0 + 32, rAH1 = rAL1 + 32;
    const int rBL = (wave >> 2) * 64 + (wave & 3) * 8;
    const int rBH = rBL + 32;

#define SGA(kk, r, bsel) gld_lds16(gU + (size_t)(r) * op.ldu + (kk), &As[bsel][(r) * BK])
#define SGB(kk, r, bsel) gld_lds16(gV + (size_t)(r) * op.ldv + (kk), &Bs[bsel][(r) * BK])

    f32x4 acc[4][4];
#pragma unroll
    for (int i = 0; i < 4; ++i)
#pragma unroll
        for (int j = 0; j < 4; ++j) acc[i][j] = (f32x4){0.f, 0.f, 0.f, 0.f};

    const int l15 = lane & 15;
    const int cx0 = (lane >> 4) ^ (lane & 7);        // phys chunk, k-step 0
    const int cx1 = (4 | (lane >> 4)) ^ (lane & 7);  // phys chunk, k-step 1

    const int NT = op.K / BK;                 // even (8 or 32)

    // prologue: tile 0 -> buf 0 in deadline order; certify {BLo,ALo0,ALo1};
    // pre-read b_lo(0).
    SGB(0, rBL, 0); SGA(0, rAL0, 0); SGA(0, rAL1, 0);
    SGB(0, rBH, 0); SGA(0, rAH0, 0); SGA(0, rAH1, 0);
    asm volatile("s_waitcnt vmcnt(3)" ::: "memory");
    __builtin_amdgcn_s_barrier();
    asm volatile("" ::: "memory");

    s16x8 bL0[2][2], bL1[2][2];
    {
        const s16x8* Bp = (const s16x8*)Bs[0];
        bL0[0][0] = Bp[(wn + l15) * 8 + cx0];
        bL0[0][1] = Bp[(wn + l15) * 8 + cx1];
        bL0[1][0] = Bp[(wn + 16 + l15) * 8 + cx0];
        bL0[1][1] = Bp[(wn + 16 + l15) * 8 + cx1];
    }

#define TILE(T, CB, NB, BCUR, BNXT) do {                                      \
    const bool s1_ = ((T) + 1) < NT;                                          \
    const int kn_ = ((T) + 1) * BK;                                           \
    const s16x8* Ap_ = (const s16x8*)As[CB];                                  \
    const s16x8* Bp_ = (const s16x8*)Bs[CB];                                  \
    const s16x8* Bn_ = (const s16x8*)Bs[NB];                                  \
    s16x8 al_[2][2], ah_[2][2], bh_[2][2];                                    \
    /* P0: reads a_lo; stage BLo,ALo0(T+1); Q0=(iLo,jLo) */                   \
    al_[0][0] = Ap_[(wm + l15) * 8 + cx0];                                    \
    al_[0][1] = Ap_[(wm + l15) * 8 + cx1];                                    \
    al_[1][0] = Ap_[(wm + 16 + l15) * 8 + cx0];                               \
    al_[1][1] = Ap_[(wm + 16 + l15) * 8 + cx1];                               \
    if (s1_) { SGB(kn_, rBL, NB); SGA(kn_, rAL0, NB); }                       \
    if (s1_) asm volatile("s_waitcnt vmcnt(4)" ::: "memory");                 \
    else     asm volatile("s_waitcnt vmcnt(2)" ::: "memory");                 \
    __builtin_amdgcn_s_barrier();                                             \
    asm volatile("s_waitcnt lgkmcnt(0)" ::: "memory");                        \
    __builtin_amdgcn_sched_barrier(0);                                        \
    __builtin_amdgcn_s_setprio(1);                                            \
    _Pragma("unroll") for (int s = 0; s < 2; ++s)                             \
        _Pragma("unroll") for (int i = 0; i < 2; ++i)                         \
            _Pragma("unroll") for (int j = 0; j < 2; ++j)                     \
                acc[i][j] = __builtin_amdgcn_mfma_f32_16x16x32_bf16(          \
                    al_[i][s], BCUR[j][s], acc[i][j], 0, 0, 0);               \
    __builtin_amdgcn_s_setprio(0);                                            \
    asm volatile("" ::: "memory");                                            \
    __builtin_amdgcn_s_barrier();                                             \
    asm volatile("" ::: "memory");                                            \
    /* P1: reads b_hi; stage ALo1,BHi(T+1); Q1=(iLo,jHi) */                   \
    bh_[0][0] = Bp_[(wn + 32 + l15) * 8 + cx0];                               \
    bh_[0][1] = Bp_[(wn + 32 + l15) * 8 + cx1];                               \
    bh_[1][0] = Bp_[(wn + 48 + l15) * 8 + cx0];                               \
    bh_[1][1] = Bp_[(wn + 48 + l15) * 8 + cx1];                               \
    if (s1_) { SGA(kn_, rAL1, NB); SGB(kn_, rBH, NB); }                       \
    if (s1_) asm volatile("s_waitcnt vmcnt(4)" ::: "memory");                 \
    else     asm volatile("s_waitcnt vmcnt(0)" ::: "memory");                 \
    __builtin_amdgcn_s_barrier();                                             \
    asm volatile("s_waitcnt lgkmcnt(0)" ::: "memory");                        \
    __builtin_amdgcn_sched_barrier(0);                                        \
    __builtin_amdgcn_s_setprio(1);                                            \
    _Pragma("unroll") for (int s = 0; s < 2; ++s)                             \
        _Pragma("unroll") for (int i = 0; i < 2; ++i)                         \
            _Pragma("unroll") for (int j = 0; j < 2; ++j)                     \
                acc[i][2 + j] = __builtin_amdgcn_mfma_f32_16x16x32_bf16(      \
                    al_[i][s], bh_[j][s], acc[i][2 + j], 0, 0, 0);            \
    __builtin_amdgcn_s_setprio(0);                                            \
    asm volatile("" ::: "memory");                                            \
    __builtin_amdgcn_s_barrier();                                             \
    asm volatile("" ::: "memory");                                            \
    /* P2: reads a_hi; stage AHi0,AHi1(T+1); Q2=(iHi,jHi) */                  \
    ah_[0][0] = Ap_[(wm + 32 + l15) * 8 + cx0];                               \
    ah_[0][1] = Ap_[(wm + 32 + l15) * 8 + cx1];                               \
    ah_[1][0] = Ap_[(wm + 48 + l15) * 8 + cx0];                               \
    ah_[1][1] = Ap_[(wm + 48 + l15) * 8 + cx1];                               \
    if (s1_) { SGA(kn_, rAH0, NB); SGA(kn_, rAH1, NB); }                      \
    if (s1_) asm volatile("s_waitcnt vmcnt(5)" ::: "memory");                 \
    __builtin_amdgcn_s_barrier();                                             \
    asm volatile("s_waitcnt lgkmcnt(0)" ::: "memory");                        \
    __builtin_amdgcn_sched_barrier(0);                                        \
    __builtin_amdgcn_s_setprio(1);                                            \
    _Pragma("unroll") for (int s = 0; s < 2; ++s)                             \
        _Pragma("unroll") for (int i = 0; i < 2; ++i)                         \
            _Pragma("unroll") for (int j = 0; j < 2; ++j)                     \
                acc[2 + i][2 + j] = __builtin_amdgcn_mfma_f32_16x16x32_bf16(  \
                    ah_[i][s], bh_[j][s], acc[2 + i][2 + j], 0, 0, 0);        \
    __builtin_amdgcn_s_setprio(0);                                            \
    asm volatile("" ::: "memory");                                            \
    __builtin_amdgcn_s_barrier();                                             \
    asm volatile("" ::: "memory");                                            \
    /* P3: pre-read b_lo(T+1) (overlaps MFMA); Q3=(iHi,jLo) */                \
    __builtin_amdgcn_s_setprio(1);                                            \
    _Pragma("unroll") for (int s = 0; s < 2; ++s)                             \
        _Pragma("unroll") for (int i = 0; i < 2; ++i)                         \
            _Pragma("unroll") for (int j = 0; j < 2; ++j)                     \
                acc[2 + i][j] = __builtin_amdgcn_mfma_f32_16x16x32_bf16(      \
                    ah_[i][s], BCUR[j][s], acc[2 + i][j], 0, 0, 0);           \
    __builtin_amdgcn_s_setprio(0);                                            \
    if (s1_) {                                                                \
        BNXT[0][0] = Bn_[(wn + l15) * 8 + cx0];                               \
        BNXT[0][1] = Bn_[(wn + l15) * 8 + cx1];                               \
        BNXT[1][0] = Bn_[(wn + 16 + l15) * 8 + cx0];                          \
        BNXT[1][1] = Bn_[(wn + 16 + l15) * 8 + cx1];                          \
        asm volatile("s_waitcnt vmcnt(3)" ::: "memory");                      \
    }                                                                         \
    asm volatile("" ::: "memory");                                            \
    __builtin_amdgcn_s_barrier();                                             \
    asm volatile("" ::: "memory");                                            \
} while (0)

    for (int t = 0; t < NT; t += 2) {
        TILE(t, 0, 1, bL0, bL1);
        TILE(t + 1, 1, 0, bL1, bL0);
    }
#undef TILE
#undef SGA
#undef SGB

    // ---- epilogue ----  C/D layout: col=lane&15, row=(lane>>4)*4+r
    const int ldo = op.ldo;
    const int ccol = lane & 15;
    const int crow = (lane >> 4) * 4;
#pragma unroll
    for (int i = 0; i < 4; ++i) {
#pragma unroll
        for (int j = 0; j < 4; ++j) {
            const int gr0 = bm * BM + wm + i * 16 + crow;
            const int gc = bn * BN + wn + j * 16 + ccol;
            float v[4];
#pragma unroll
            for (int r = 0; r < 4; ++r) {
                v[r] = acc[i][j][r];
                if (op.Add) v[r] += op.Add[(size_t)(gr0 + r) * ldo + gc];
            }
            if (op.OutB) {
#pragma unroll
                for (int r = 0; r < 4; ++r)
                    op.OutB[(size_t)(gr0 + r) * ldo + gc] = f32_to_bf16(v[r]);
            }
            if (op.OutT) {
                uint2 u;
                u.x = (uint32_t)f32_to_bf16(v[0]) | ((uint32_t)f32_to_bf16(v[1]) << 16);
                u.y = (uint32_t)f32_to_bf16(v[2]) | ((uint32_t)f32_to_bf16(v[3]) << 16);
                *(uint2*)(&op.OutT[(size_t)gc * ldo + gr0]) = u;   // gr0 % 4 == 0
            }
            if (op.OutF) {
#pragma unroll
                for (int r = 0; r < 4; ++r)
                    op.OutF[(size_t)(gr0 + r) * ldo + gc] = v[r];
            }
        }
    }
}

static inline GemmOp mkop(const u16* U, const u16* V, int K, int ldu, int ldv,
                          const float* Add, u16* OutB, u16* OutT, float* OutF,
                          int N = 2048, int ldo = 2048) {
    GemmOp o;
    o.U = U; o.V = V; o.Add = Add; o.OutB = OutB; o.OutT = OutT; o.OutF = OutF;
    o.K = K; o.ldu = ldu; o.ldv = ldv; o.N = N; o.ldo = ldo;
    return o;
}

extern "C" void kernel_launch(void* const* d_in, const int* in_sizes, int n_in,
                              void* d_out, int out_size, void* d_ws, size_t ws_size,
                              hipStream_t stream) {
    const float* A = (const float*)d_in[0];     // (2048, 2048)
    const float* A_F = (const float*)d_in[1];   // (2048, 2048)
    const float* C = (const float*)d_in[2];     // (512, 2048)
    const float* C_F = (const float*)d_in[3];   // (512, 2048)
    const int n = 2048, p = 512;
    (void)in_sizes; (void)n_in; (void)out_size; (void)ws_size;

    char* ws = (char*)d_ws;
    const size_t MB = 1u << 20;
    // ---- Smith squaring, 5 levels -> S_32.
    // Tail bound: sigma_max(A),(B) ~ 0.909 (Ginibre 2*sqrt(n)*s), so
    // |S_50 - S_32| <= 20*0.909^64/0.174 ~ 0.25 absmax (<=0.62 at sigma=0.92);
    // + bf16 path 0.5 -> ~1.1 total, under the 2.33 threshold.
    // Level 0 rank-512: B R_0 A = (B C_F^T)(C A)^T = W1 Y^T (0.75 GEMM-units).
    u16* AT   = (u16*)(ws + 0 * MB);    // A^T  bf16  (A_0 transposed form)
    u16* Ab   = (u16*)(ws + 8 * MB);    // A    bf16  (A_0 row form)
    u16* AFT  = (u16*)(ws + 16 * MB);   // B=A_F^T row bf16 (B_0 row form)
    u16* AFb  = (u16*)(ws + 24 * MB);   // A_F  bf16  (B_0 transposed form)
    u16* CFT  = (u16*)(ws + 32 * MB);   // C_F^T bf16 (2048x512)
    u16* CT   = (u16*)(ws + 34 * MB);   // C^T   bf16 (2048x512)
    float* R32 = (float*)(ws + 36 * MB);// running R fp32
    u16* Rb   = (u16*)(ws + 52 * MB);   // running R bf16 row
    u16* XT   = (u16*)(ws + 60 * MB);   // (R*A_i)^T bf16 — used from level 1 on
    u16* W1b  = (u16*)(ws + 60 * MB);   // W1 = B C_F^T bf16 (2048x512, level 0 only)
    u16* Yb   = (u16*)(ws + 62 * MB);   // Y = A^T C^T bf16 (2048x512, level 0 only)
    u16* CFb  = (u16*)(ws + 64 * MB);   // C_F bf16 row (512x2048, level 0 only)
    u16* Cb   = (u16*)(ws + 66 * MB);   // C   bf16 row (512x2048, level 0 only)
    u16* Tb1  = (u16*)(ws + 68 * MB);   // ping-pong set 1: B_i row
    u16* TbT1 = (u16*)(ws + 76 * MB);   //                  B_i^T
    u16* Ub1  = (u16*)(ws + 84 * MB);   //                  A_i row
    u16* UbT1 = (u16*)(ws + 92 * MB);   //                  A_i^T

    dim3 tb(32, 8);
    stein_transpose_f32_bf16<<<dim3(64, 64), tb, 0, stream>>>(A, AT, n, n);
    stein_convert_f32_bf16<<<4096, 256, 0, stream>>>(A, Ab, n * n);
    stein_transpose_f32_bf16<<<dim3(64, 64), tb, 0, stream>>>(A_F, AFT, n, n);
    stein_convert_f32_bf16<<<4096, 256, 0, stream>>>(A_F, AFb, n * n);
    stein_transpose_f32_bf16<<<dim3(64, 16), tb, 0, stream>>>(C_F, CFT, p, n);
    stein_transpose_f32_bf16<<<dim3(64, 16), tb, 0, stream>>>(C, CT, p, n);
    stein_convert_f32_bf16<<<1024, 256, 0, stream>>>(C_F, CFb, p * n);
    stein_convert_f32_bf16<<<1024, 256, 0, stream>>>(C, Cb, p * n);

    u16* Tb[2]  = {AFT, Tb1};
    u16* TbT[2] = {AFb, TbT1};
    u16* Ub[2]  = {Ab, Ub1};
    u16* UbT[2] = {AT, UbT1};

    dim3 blk(512);
    dim3 g1(8, 16, 1), g2(8, 16, 2), g5(8, 16, 5);

    // d0 (z=5): level-0 independent ops. Long K=2048 ops at low z so
    // stragglers are the short-K R0 blocks.
    {
        GemmOp oW1  = mkop(AFT, CFb, n, n, n, nullptr, W1b, nullptr, nullptr, p, p);
        GemmOp oY   = mkop(AT, Cb, n, n, n, nullptr, Yb, nullptr, nullptr, p, p);
        GemmOp oAsq = mkop(Ub[0], UbT[0], n, n, n, nullptr, Ub[1], UbT[1], nullptr);
        GemmOp oBsq = mkop(Tb[0], TbT[0], n, n, n, nullptr, Tb[1], TbT[1], nullptr);
        GemmOp oR0  = mkop(CFT, CT, p, p, p, nullptr, nullptr, nullptr, R32);
        stein_gemm_nt2<<<g5, blk, 0, stream>>>(oW1, oY, oAsq, oBsq, oR0);
    }
    // d0b: R_1 = W1 Y^T + R_0  (K=512)
    {
        GemmOp oRup = mkop(W1b, Yb, p, p, p, R32, Rb, nullptr, R32);
        stein_gemm_nt2<<<g1, blk, 0, stream>>>(oRup, oRup, oRup, oRup, oRup);
    }

    // levels 1..3: full doubling, stream-sharing pairing.
    // R_j = S_{2^j}; after level 3: R_4 = S_16, A_4 = A^16 in set 0.
    // Level 3 skips dead outputs: Ub[0] row form and TbT[0] (level 4 uses
    // only UbT[0] and Tb[0]).
    for (int i = 1; i < 4; ++i) {
        const int c = i & 1, nx = c ^ 1;
        GemmOp oXT = mkop(Rb, UbT[c], n, n, n, nullptr, nullptr, XT, nullptr);
        // d1: {XT = R A_i, Asq = A_i^2} — shared V stream = A_i^T.
        GemmOp oAsq = mkop(Ub[c], UbT[c], n, n, n, nullptr,
                           (i == 3) ? nullptr : Ub[nx], UbT[nx], nullptr);
        stein_gemm_nt2<<<g2, blk, 0, stream>>>(oXT, oAsq, oAsq, oAsq, oAsq);
        // d2: {Rup = B_i X + R, Bsq = B_i^2} — shared U stream = B_i.
        GemmOp oRup = mkop(Tb[c], XT, n, n, n, R32, Rb, nullptr, R32);
        GemmOp oBsq = mkop(Tb[c], TbT[c], n, n, n, nullptr, Tb[nx],
                           (i == 3) ? nullptr : TbT[nx], nullptr);
        stein_gemm_nt2<<<g2, blk, 0, stream>>>(oRup, oBsq, oBsq, oBsq, oBsq);
    }

    // level 4 (final): S_32 = R_4 + B_4 (R_4 A_4) -> d_out. A_4/B_4 in set 0.
    {
        const int c = 0;
        GemmOp oXT = mkop(Rb, UbT[c], n, n, n, nullptr, nullptr, XT, nullptr);
        stein_gemm_nt2<<<g1, blk, 0, stream>>>(oXT, oXT, oXT, oXT, oXT);
        GemmOp oFin = mkop(Tb[c], XT, n, n, n, R32, nullptr, nullptr, (float*)d_out);
        stein_gemm_nt2<<<g1, blk, 0, stream>>>(oFin, oFin, oFin, oFin, oFin);
    }
}

// Round 5
// 486.665 us; speedup vs baseline: 1.6986x; 1.3108x over previous
//
#include <hip/hip_runtime.h>
#include <hip/hip_bf16.h>
#include <stdint.h>

typedef __attribute__((ext_vector_type(4))) float f32x4;
typedef __attribute__((ext_vector_type(8))) short s16x8;
typedef unsigned short u16;
typedef unsigned int u32;

#define BM 128
#define BN 128
#define BK 64

// round-to-nearest-even f32 -> bf16 (bit pattern)
__device__ __forceinline__ u16 f32_to_bf16(float f) {
    uint32_t u = __float_as_uint(f);
    u = u + 0x7FFFu + ((u >> 16) & 1u);
    return (u16)(u >> 16);
}

__device__ __forceinline__ void gld_lds16(const void* g, void* l) {
    __builtin_amdgcn_global_load_lds(
        (const __attribute__((address_space(1))) uint32_t*)g,
        (__attribute__((address_space(3))) uint32_t*)l,
        16, 0, 0);
}

// R17 prep fusion: one read of the fp32 input produces BOTH the straight
// bf16 form and the transposed bf16 form (was 2 kernels / 2 reads each).
__global__ void stein_prep_sq(const float* __restrict__ in, u16* __restrict__ outB,
                              u16* __restrict__ outT, int N2) {
    __shared__ float tile[32][33];
    const int tx = threadIdx.x, ty = threadIdx.y;     // 32 x 8
    const int c0 = blockIdx.x * 32, r0 = blockIdx.y * 32;
#pragma unroll
    for (int i = 0; i < 32; i += 8) {
        float v = in[(size_t)(r0 + ty + i) * N2 + (c0 + tx)];
        outB[(size_t)(r0 + ty + i) * N2 + (c0 + tx)] = f32_to_bf16(v);
        tile[ty + i][tx] = v;
    }
    __syncthreads();
#pragma unroll
    for (int i = 0; i < 32; i += 8)
        outT[(size_t)(c0 + ty + i) * N2 + (r0 + tx)] = f32_to_bf16(tile[tx][ty + i]);
}

// Rect prep: in is R x C; outB = straight bf16 (R x C); outT = transpose
// (C x R) with row stride ldoT (lands in the left half of the K-concat
// buffers for the d0b fold).
__global__ void stein_prep_rect(const float* __restrict__ in, u16* __restrict__ outB,
                                u16* __restrict__ outT, int R, int C, int ldoT) {
    __shared__ float tile[32][33];
    const int tx = threadIdx.x, ty = threadIdx.y;     // 32 x 8
    const int c0 = blockIdx.x * 32, r0 = blockIdx.y * 32;
#pragma unroll
    for (int i = 0; i < 32; i += 8) {
        float v = in[(size_t)(r0 + ty + i) * C + (c0 + tx)];
        outB[(size_t)(r0 + ty + i) * C + (c0 + tx)] = f32_to_bf16(v);
        tile[ty + i][tx] = v;
    }
    __syncthreads();
#pragma unroll
    for (int i = 0; i < 32; i += 8)
        outT[(size_t)(c0 + ty + i) * ldoT + (r0 + tx)] = f32_to_bf16(tile[tx][ty + i]);
}

// Runtime-descriptor GEMM op: C[m,n] = sum_k U[m,k] V[n,k]  (NT, bf16 in).
struct GemmOp {
    const u16* U; const u16* V;
    const float* Add;
    u16* OutB; u16* OutT; float* OutF;
    int K, ldu, ldv, N, ldo;
};

// R17 = R12 K-loop verbatim (the measured-best structure: 128x128x64,
// 4 waves, 2 blocks/CU — R13-R16's 8-wave/1-block schedules all regressed;
// the 2nd independent block per CU is the working latency-hiding mechanism)
// + NEW epilogue: OutT via LDS bounce. R12's OutT path was a uint2 scatter
// at 4 KB stride (1 dirty line per 8 B store -> WRITE_SIZE 61 MB vs ~40
// logical). The staging LDS (64 KB) is dead after the K-loop: stage the
// C-tile as T[col][row] (pad 132 to spread banks) and write OutT rows
// coalesced 16 B/lane. Add never coexists with OutT (XT/Asq/Bsq ops only).
// Bank swizzle in K-loop (0 conflicts measured): physical chunk p of row r
// holds logical chunk p ^ (r&7); readers use (s*4+(lane>>4)) ^ (lane&7).
__global__ __launch_bounds__(256, 2) void stein_gemm_nt2(GemmOp op0, GemmOp op1,
                                                         GemmOp op2, GemmOp op3,
                                                         GemmOp op4) {
    const int z = blockIdx.z;
    const GemmOp op = (z == 0) ? op0 : (z == 1) ? op1 : (z == 2) ? op2
                      : (z == 3) ? op3 : op4;
    const int bm = blockIdx.x, bn = blockIdx.y;
    if (bn * BN >= op.N) return;              // rectangular (N=512) ops

    __shared__ alignas(16) short SMEM[32768];      // 64 KB: Us[2] | Vs[2]
    short* Us0 = SMEM;                             // 2 x BM*BK
    short* Vs0 = SMEM + 2 * BM * BK;               // 2 x BN*BK

    const int t = threadIdx.x;
    const int wave = t >> 6;
    const int lane = t & 63;
    const int wm = (wave >> 1) * 64;
    const int wn = (wave & 1) * 64;

    // staging: wave w covers rows [32w, 32w+32) of U and V; 4 DMA ops each
    // (8 rows x 128 B per op).
    const int lrow8 = lane >> 3;                  // 0..7
    const int lchunk = (lane & 7) ^ lrow8;        // swizzled source chunk
    const u16* gU = op.U + (size_t)(bm * BM + wave * 32 + lrow8) * op.ldu + lchunk * 8;
    const u16* gV = op.V + (size_t)(bn * BN + wave * 32 + lrow8) * op.ldv + lchunk * 8;
    short* sU = Us0 + (wave * 32) * BK;
    short* sV = Vs0 + (wave * 32) * BK;
    const int bufU = BM * BK;                     // elements per buffer
    const int bufV = BN * BK;

    f32x4 acc[4][4];
#pragma unroll
    for (int i = 0; i < 4; ++i)
#pragma unroll
        for (int j = 0; j < 4; ++j) acc[i][j] = (f32x4){0.f, 0.f, 0.f, 0.f};

    const int arow = wm + (lane & 15);
    const int brow = wn + (lane & 15);

    // prologue: stage tile 0 into buffer 0
#pragma unroll
    for (int j = 0; j < 4; ++j) {
        gld_lds16(gU + (size_t)(8 * j) * op.ldu, sU + j * 512);
        gld_lds16(gV + (size_t)(8 * j) * op.ldv, sV + j * 512);
    }

    int buf = 0;
    for (int kk = 0; kk < op.K; kk += BK) {
        __syncthreads();   // buffer `buf` staged; prior reads of buf^1 done
        if (kk + BK < op.K) {
            const int kn = kk + BK;
            const int bo = buf ^ 1;
#pragma unroll
            for (int j = 0; j < 4; ++j) {
                gld_lds16(gU + (size_t)(8 * j) * op.ldu + kn, sU + bo * bufU + j * 512);
                gld_lds16(gV + (size_t)(8 * j) * op.ldv + kn, sV + bo * bufV + j * 512);
            }
        }
#pragma unroll
        for (int s = 0; s < 2; ++s) {
            const int cx = (s * 4 + (lane >> 4)) ^ (lane & 7);   // phys chunk
            s16x8 af[4], bfr[4];
#pragma unroll
            for (int i = 0; i < 4; ++i)
                af[i] = ((const s16x8*)(Us0 + (size_t)buf * bufU))[(arow + i * 16) * (BK / 8) + cx];
#pragma unroll
            for (int j = 0; j < 4; ++j)
                bfr[j] = ((const s16x8*)(Vs0 + (size_t)buf * bufV))[(brow + j * 16) * (BK / 8) + cx];
#pragma unroll
            for (int i = 0; i < 4; ++i)
#pragma unroll
                for (int j = 0; j < 4; ++j)
                    acc[i][j] = __builtin_amdgcn_mfma_f32_16x16x32_bf16(
                        af[i], bfr[j], acc[i][j], 0, 0, 0);
        }
        buf ^= 1;
    }

    // ---- epilogue ----  C/D layout: col=lane&15, row=(lane>>4)*4+r
    const int ldo = op.ldo;
    const int ccol = lane & 15;
    const int crow = (lane >> 4) * 4;

    // pass 1: row-major outputs straight from registers (+ optional Add)
    if (op.OutB || op.OutF) {
#pragma unroll
        for (int i = 0; i < 4; ++i) {
#pragma unroll
            for (int j = 0; j < 4; ++j) {
                const int gr0 = bm * BM + wm + i * 16 + crow;
                const int gc = bn * BN + wn + j * 16 + ccol;
                float v[4];
#pragma unroll
                for (int r = 0; r < 4; ++r) {
                    v[r] = acc[i][j][r];
                    if (op.Add) v[r] += op.Add[(size_t)(gr0 + r) * ldo + gc];
                }
                if (op.OutB) {
#pragma unroll
                    for (int r = 0; r < 4; ++r)
                        op.OutB[(size_t)(gr0 + r) * ldo + gc] = f32_to_bf16(v[r]);
                }
                if (op.OutF) {
#pragma unroll
                    for (int r = 0; r < 4; ++r)
                        op.OutF[(size_t)(gr0 + r) * ldo + gc] = v[r];
                }
            }
        }
    }

    // pass 2: transposed bf16 via LDS bounce (staging LDS is dead now).
    // T[col][row], stride 132 u16 (bank spread). Coalesced 16 B/lane rows.
    if (op.OutT) {
        __syncthreads();                   // all K-loop LDS reads complete
        u16* T = (u16*)SMEM;               // 128*132*2 = 33792 B <= 64 KB
#pragma unroll
        for (int i = 0; i < 4; ++i) {
#pragma unroll
            for (int j = 0; j < 4; ++j) {
                const int c_ = wn + j * 16 + ccol;
                const int r_ = wm + i * 16 + crow;      // multiple of 4
                uint2 w;
                w.x = (u32)f32_to_bf16(acc[i][j][0]) | ((u32)f32_to_bf16(acc[i][j][1]) << 16);
                w.y = (u32)f32_to_bf16(acc[i][j][2]) | ((u32)f32_to_bf16(acc[i][j][3]) << 16);
                *(uint2*)&T[c_ * 132 + r_] = w;
            }
        }
        __syncthreads();
        const int cpart = t >> 4;          // 0..15: column within pass
        const int m = t & 15;              // 16 B chunk along the row
#pragma unroll
        for (int k2 = 0; k2 < 8; ++k2) {
            const int c_ = k2 * 16 + cpart;
            uint2 x = *(const uint2*)&T[c_ * 132 + m * 8];
            uint2 y = *(const uint2*)&T[c_ * 132 + m * 8 + 4];
            uint4 w; w.x = x.x; w.y = x.y; w.z = y.x; w.w = y.y;
            *(uint4*)&op.OutT[(size_t)(bn * BN + c_) * ldo + bm * BM + m * 8] = w;
        }
    }
}

static inline GemmOp mkop(const u16* U, const u16* V, int K, int ldu, int ldv,
                          const float* Add, u16* OutB, u16* OutT, float* OutF,
                          int N = 2048, int ldo = 2048) {
    GemmOp o;
    o.U = U; o.V = V; o.Add = Add; o.OutB = OutB; o.OutT = OutT; o.OutF = OutF;
    o.K = K; o.ldu = ldu; o.ldv = ldv; o.N = N; o.ldo = ldo;
    return o;
}

extern "C" void kernel_launch(void* const* d_in, const int* in_sizes, int n_in,
                              void* d_out, int out_size, void* d_ws, size_t ws_size,
                              hipStream_t stream) {
    const float* A = (const float*)d_in[0];     // (2048, 2048)
    const float* A_F = (const float*)d_in[1];   // (2048, 2048)
    const float* C = (const float*)d_in[2];     // (512, 2048)
    const float* C_F = (const float*)d_in[3];   // (512, 2048)
    const int n = 2048, p = 512;
    (void)in_sizes; (void)n_in; (void)out_size; (void)ws_size;

    char* ws = (char*)d_ws;
    const size_t MB = 1u << 20;
    // ---- Smith squaring, 5 levels -> S_32 (tail bound: see R12 notes;
    // absmax 0.5 measured, threshold 2.33).
    // R17 d0b-fold: R_1 = [CFT|W1] [CT|Y]^T in ONE K=1024 GEMM (kills the
    // separate R0 op + its 16 MB write + 16 MB Add read; fp32 acc over the
    // whole K — numerics same or better).
    u16* AT   = (u16*)(ws + 0 * MB);    // A^T  bf16  (A_0 transposed form)
    u16* Ab   = (u16*)(ws + 8 * MB);    // A    bf16  (A_0 row form)
    u16* AFT  = (u16*)(ws + 16 * MB);   // B=A_F^T row bf16 (B_0 row form)
    u16* AFb  = (u16*)(ws + 24 * MB);   // A_F  bf16  (B_0 transposed form)
    u16* WYU  = (u16*)(ws + 32 * MB);   // 2048x1024: [CFT | W1=B C_F^T]
    u16* WYV  = (u16*)(ws + 36 * MB);   // 2048x1024: [CT  | Y=A^T C^T]
    u16* XT   = (u16*)(ws + 32 * MB);   // (R A_i)^T — overlaps WYU/WYV (dead after d0b)
    float* R32 = (float*)(ws + 40 * MB);// running R fp32
    u16* Rb   = (u16*)(ws + 56 * MB);   // running R bf16 row
    u16* CFb  = (u16*)(ws + 64 * MB);   // C_F bf16 row (level 0 only)
    u16* Cb   = (u16*)(ws + 66 * MB);   // C   bf16 row (level 0 only)
    u16* Tb1  = (u16*)(ws + 68 * MB);   // ping-pong set 1: B_i row
    u16* TbT1 = (u16*)(ws + 76 * MB);   //                  B_i^T
    u16* Ub1  = (u16*)(ws + 84 * MB);   //                  A_i row
    u16* UbT1 = (u16*)(ws + 92 * MB);   //                  A_i^T   (top = 100 MB)

    dim3 tb(32, 8);
    stein_prep_sq<<<dim3(64, 64), tb, 0, stream>>>(A, Ab, AT, n);
    stein_prep_sq<<<dim3(64, 64), tb, 0, stream>>>(A_F, AFb, AFT, n);
    stein_prep_rect<<<dim3(64, 16), tb, 0, stream>>>(C_F, CFb, WYU, p, n, 2 * p);
    stein_prep_rect<<<dim3(64, 16), tb, 0, stream>>>(C, Cb, WYV, p, n, 2 * p);

    u16* Tb[2]  = {AFT, Tb1};
    u16* TbT[2] = {AFb, TbT1};
    u16* Ub[2]  = {Ab, Ub1};
    u16* UbT[2] = {AT, UbT1};

    dim3 blk(256);
    dim3 g1(16, 16, 1), g2(16, 16, 2), g4(16, 16, 4);

    // d0 (z=4): level-0 independent ops. Long K=2048 small-N ops at LOW z
    // (dispatched first) so stragglers are short.
    {
        GemmOp oW1  = mkop(AFT, CFb, n, n, n, nullptr, WYU + p, nullptr, nullptr, p, 2 * p);
        GemmOp oY   = mkop(AT, Cb, n, n, n, nullptr, WYV + p, nullptr, nullptr, p, 2 * p);
        GemmOp oAsq = mkop(Ub[0], UbT[0], n, n, n, nullptr, Ub[1], UbT[1], nullptr);
        GemmOp oBsq = mkop(Tb[0], TbT[0], n, n, n, nullptr, Tb[1], TbT[1], nullptr);
        stein_gemm_nt2<<<g4, blk, 0, stream>>>(oW1, oY, oAsq, oBsq, oBsq);
    }
    // d0b: R_1 = [CFT|W1] [CT|Y]^T  (K=1024 concat = RHS + B RHS A)
    {
        GemmOp oR1 = mkop(WYU, WYV, 2 * p, 2 * p, 2 * p, nullptr, Rb, nullptr, R32);
        stein_gemm_nt2<<<g1, blk, 0, stream>>>(oR1, oR1, oR1, oR1, oR1);
    }

    // levels 1..3: full doubling, stream-sharing pairing.
    // R_j = S_{2^j}; after level 3: R_4 = S_16, A_4 = A^16 in set 0.
    // Level 3 drops dead outputs (level 4 needs only UbT[0] and Tb[0]).
    for (int i = 1; i < 4; ++i) {
        const int c = i & 1, nx = c ^ 1;
        GemmOp oXT = mkop(Rb, UbT[c], n, n, n, nullptr, nullptr, XT, nullptr);
        // d1: {XT = R A_i, Asq = A_i^2} — shared V stream = A_i^T.
        GemmOp oAsq = mkop(Ub[c], UbT[c], n, n, n, nullptr,
                           (i == 3) ? nullptr : Ub[nx], UbT[nx], nullptr);
        stein_gemm_nt2<<<g2, blk, 0, stream>>>(oXT, oAsq, oAsq, oAsq, oAsq);
        // d2: {Rup = B_i X + R, Bsq = B_i^2} — shared U stream = B_i.
        GemmOp oRup = mkop(Tb[c], XT, n, n, n, R32, Rb, nullptr, R32);
        GemmOp oBsq = mkop(Tb[c], TbT[c], n, n, n, nullptr, Tb[nx],
                           (i == 3) ? nullptr : TbT[nx], nullptr);
        stein_gemm_nt2<<<g2, blk, 0, stream>>>(oRup, oBsq, oBsq, oBsq, oBsq);
    }

    // level 4 (final): S_32 = R_4 + B_4 (R_4 A_4) -> d_out. A_4/B_4 in set 0.
    {
        const int c = 0;
        GemmOp oXT = mkop(Rb, UbT[c], n, n, n, nullptr, nullptr, XT, nullptr);
        stein_gemm_nt2<<<g1, blk, 0, stream>>>(oXT, oXT, oXT, oXT, oXT);
        GemmOp oFin = mkop(Tb[c], XT, n, n, n, R32, nullptr, nullptr, (float*)d_out);
        stein_gemm_nt2<<<g1, blk, 0, stream>>>(oFin, oFin, oFin, oFin, oFin);
    }
}

// Round 6
// 475.087 us; speedup vs baseline: 1.7400x; 1.0244x over previous
//
#include <hip/hip_runtime.h>
#include <hip/hip_bf16.h>
#include <stdint.h>

typedef __attribute__((ext_vector_type(4))) float f32x4;
typedef __attribute__((ext_vector_type(8))) short s16x8;
typedef unsigned short u16;
typedef unsigned int u32;

#define BM 128
#define BN 128
#define BK 64

// round-to-nearest-even f32 -> bf16 (bit pattern)
__device__ __forceinline__ u16 f32_to_bf16(float f) {
    uint32_t u = __float_as_uint(f);
    u = u + 0x7FFFu + ((u >> 16) & 1u);
    return (u16)(u >> 16);
}

__device__ __forceinline__ void gld_lds16(const void* g, void* l) {
    __builtin_amdgcn_global_load_lds(
        (const __attribute__((address_space(1))) uint32_t*)g,
        (__attribute__((address_space(3))) uint32_t*)l,
        16, 0, 0);
}

// R17 prep fusion: one read of the fp32 input produces BOTH the straight
// bf16 form and the transposed bf16 form (was 2 kernels / 2 reads each).
__global__ void stein_prep_sq(const float* __restrict__ in, u16* __restrict__ outB,
                              u16* __restrict__ outT, int N2) {
    __shared__ float tile[32][33];
    const int tx = threadIdx.x, ty = threadIdx.y;     // 32 x 8
    const int c0 = blockIdx.x * 32, r0 = blockIdx.y * 32;
#pragma unroll
    for (int i = 0; i < 32; i += 8) {
        float v = in[(size_t)(r0 + ty + i) * N2 + (c0 + tx)];
        outB[(size_t)(r0 + ty + i) * N2 + (c0 + tx)] = f32_to_bf16(v);
        tile[ty + i][tx] = v;
    }
    __syncthreads();
#pragma unroll
    for (int i = 0; i < 32; i += 8)
        outT[(size_t)(c0 + ty + i) * N2 + (r0 + tx)] = f32_to_bf16(tile[tx][ty + i]);
}

// Rect prep: in is R x C; outB = straight bf16 (R x C); outT = transpose
// (C x R) with row stride ldoT (lands in the left half of the K-concat
// buffers for the d0b fold).
__global__ void stein_prep_rect(const float* __restrict__ in, u16* __restrict__ outB,
                                u16* __restrict__ outT, int R, int C, int ldoT) {
    __shared__ float tile[32][33];
    const int tx = threadIdx.x, ty = threadIdx.y;     // 32 x 8
    const int c0 = blockIdx.x * 32, r0 = blockIdx.y * 32;
#pragma unroll
    for (int i = 0; i < 32; i += 8) {
        float v = in[(size_t)(r0 + ty + i) * C + (c0 + tx)];
        outB[(size_t)(r0 + ty + i) * C + (c0 + tx)] = f32_to_bf16(v);
        tile[ty + i][tx] = v;
    }
    __syncthreads();
#pragma unroll
    for (int i = 0; i < 32; i += 8)
        outT[(size_t)(c0 + ty + i) * ldoT + (r0 + tx)] = f32_to_bf16(tile[tx][ty + i]);
}

// Runtime-descriptor GEMM op: C[m,n] = sum_k U[m,k] V[n,k]  (NT, bf16 in).
struct GemmOp {
    const u16* U; const u16* V;
    const float* Add;
    u16* OutB; u16* OutT; float* OutF;
    int K, ldu, ldv, N, ldo;
};

// R18 = R17 + XCD-aware block chunking. R12 K-loop verbatim (measured-best:
// 128x128x64, 4 waves, 2 blocks/CU; the 2nd independent block per CU is the
// working latency-hiding mechanism — all 8-wave/1-block schedules regressed).
// XCD swizzle: hw assigns linear wg id round-robin over 8 XCDs; default
// mapping makes every XCD read ALL 16 B panels (B re-fetched x8 -> FETCH
// ~100 MB/dispatch, staging drains eat L3/HBM latency). Remap so each XCD
// owns a 4bm x 8bn chunk: A panels x2 + B panels x4, and paired ops (z)
// hit the same chunk -> shared stream cached once per XCD. Square ops only
// (rect N=512 ops keep identity so early-exit blocks stay spread).
// Epilogue (R17): OutT via LDS bounce (staging LDS dead after K-loop),
// T[col][row] pad 132, coalesced 16 B/lane rows.
// Bank swizzle in K-loop (0 conflicts measured): physical chunk p of row r
// holds logical chunk p ^ (r&7); readers use (s*4+(lane>>4)) ^ (lane&7).
__global__ __launch_bounds__(256, 2) void stein_gemm_nt2(GemmOp op0, GemmOp op1,
                                                         GemmOp op2, GemmOp op3,
                                                         GemmOp op4) {
    const int z = blockIdx.z;
    const GemmOp op = (z == 0) ? op0 : (z == 1) ? op1 : (z == 2) ? op2
                      : (z == 3) ? op3 : op4;
    int bm = blockIdx.x, bn = blockIdx.y;
    if (op.N >= 16 * BN) {                    // square op on a 16x16 grid
        const int orig = (int)blockIdx.x + ((int)blockIdx.y << 4);
        const int xcd = orig & 7, idx = orig >> 3;
        bm = (xcd & 3) * 4 + (idx & 3);       // XCD chunk: bm in [4a,4a+4)
        bn = (xcd >> 2) * 8 + (idx >> 2);     //            bn in [8b,8b+8)
    }
    if (bn * BN >= op.N) return;              // rectangular (N=512) ops

    __shared__ alignas(16) short SMEM[32768];      // 64 KB: Us[2] | Vs[2]
    short* Us0 = SMEM;                             // 2 x BM*BK
    short* Vs0 = SMEM + 2 * BM * BK;               // 2 x BN*BK

    const int t = threadIdx.x;
    const int wave = t >> 6;
    const int lane = t & 63;
    const int wm = (wave >> 1) * 64;
    const int wn = (wave & 1) * 64;

    // staging: wave w covers rows [32w, 32w+32) of U and V; 4 DMA ops each
    // (8 rows x 128 B per op).
    const int lrow8 = lane >> 3;                  // 0..7
    const int lchunk = (lane & 7) ^ lrow8;        // swizzled source chunk
    const u16* gU = op.U + (size_t)(bm * BM + wave * 32 + lrow8) * op.ldu + lchunk * 8;
    const u16* gV = op.V + (size_t)(bn * BN + wave * 32 + lrow8) * op.ldv + lchunk * 8;
    short* sU = Us0 + (wave * 32) * BK;
    short* sV = Vs0 + (wave * 32) * BK;
    const int bufU = BM * BK;                     // elements per buffer
    const int bufV = BN * BK;

    f32x4 acc[4][4];
#pragma unroll
    for (int i = 0; i < 4; ++i)
#pragma unroll
        for (int j = 0; j < 4; ++j) acc[i][j] = (f32x4){0.f, 0.f, 0.f, 0.f};

    const int arow = wm + (lane & 15);
    const int brow = wn + (lane & 15);

    // prologue: stage tile 0 into buffer 0
#pragma unroll
    for (int j = 0; j < 4; ++j) {
        gld_lds16(gU + (size_t)(8 * j) * op.ldu, sU + j * 512);
        gld_lds16(gV + (size_t)(8 * j) * op.ldv, sV + j * 512);
    }

    int buf = 0;
    for (int kk = 0; kk < op.K; kk += BK) {
        __syncthreads();   // buffer `buf` staged; prior reads of buf^1 done
        if (kk + BK < op.K) {
            const int kn = kk + BK;
            const int bo = buf ^ 1;
#pragma unroll
            for (int j = 0; j < 4; ++j) {
                gld_lds16(gU + (size_t)(8 * j) * op.ldu + kn, sU + bo * bufU + j * 512);
                gld_lds16(gV + (size_t)(8 * j) * op.ldv + kn, sV + bo * bufV + j * 512);
            }
        }
#pragma unroll
        for (int s = 0; s < 2; ++s) {
            const int cx = (s * 4 + (lane >> 4)) ^ (lane & 7);   // phys chunk
            s16x8 af[4], bfr[4];
#pragma unroll
            for (int i = 0; i < 4; ++i)
                af[i] = ((const s16x8*)(Us0 + (size_t)buf * bufU))[(arow + i * 16) * (BK / 8) + cx];
#pragma unroll
            for (int j = 0; j < 4; ++j)
                bfr[j] = ((const s16x8*)(Vs0 + (size_t)buf * bufV))[(brow + j * 16) * (BK / 8) + cx];
#pragma unroll
            for (int i = 0; i < 4; ++i)
#pragma unroll
                for (int j = 0; j < 4; ++j)
                    acc[i][j] = __builtin_amdgcn_mfma_f32_16x16x32_bf16(
                        af[i], bfr[j], acc[i][j], 0, 0, 0);
        }
        buf ^= 1;
    }

    // ---- epilogue ----  C/D layout: col=lane&15, row=(lane>>4)*4+r
    const int ldo = op.ldo;
    const int ccol = lane & 15;
    const int crow = (lane >> 4) * 4;

    // pass 1: row-major outputs straight from registers (+ optional Add)
    if (op.OutB || op.OutF) {
#pragma unroll
        for (int i = 0; i < 4; ++i) {
#pragma unroll
            for (int j = 0; j < 4; ++j) {
                const int gr0 = bm * BM + wm + i * 16 + crow;
                const int gc = bn * BN + wn + j * 16 + ccol;
                float v[4];
#pragma unroll
                for (int r = 0; r < 4; ++r) {
                    v[r] = acc[i][j][r];
                    if (op.Add) v[r] += op.Add[(size_t)(gr0 + r) * ldo + gc];
                }
                if (op.OutB) {
#pragma unroll
                    for (int r = 0; r < 4; ++r)
                        op.OutB[(size_t)(gr0 + r) * ldo + gc] = f32_to_bf16(v[r]);
                }
                if (op.OutF) {
#pragma unroll
                    for (int r = 0; r < 4; ++r)
                        op.OutF[(size_t)(gr0 + r) * ldo + gc] = v[r];
                }
            }
        }
    }

    // pass 2: transposed bf16 via LDS bounce (staging LDS is dead now).
    // T[col][row], stride 132 u16 (bank spread). Coalesced 16 B/lane rows.
    if (op.OutT) {
        __syncthreads();                   // all K-loop LDS reads complete
        u16* T = (u16*)SMEM;               // 128*132*2 = 33792 B <= 64 KB
#pragma unroll
        for (int i = 0; i < 4; ++i) {
#pragma unroll
            for (int j = 0; j < 4; ++j) {
                const int c_ = wn + j * 16 + ccol;
                const int r_ = wm + i * 16 + crow;      // multiple of 4
                uint2 w;
                w.x = (u32)f32_to_bf16(acc[i][j][0]) | ((u32)f32_to_bf16(acc[i][j][1]) << 16);
                w.y = (u32)f32_to_bf16(acc[i][j][2]) | ((u32)f32_to_bf16(acc[i][j][3]) << 16);
                *(uint2*)&T[c_ * 132 + r_] = w;
            }
        }
        __syncthreads();
        const int cpart = t >> 4;          // 0..15: column within pass
        const int m = t & 15;              // 16 B chunk along the row
#pragma unroll
        for (int k2 = 0; k2 < 8; ++k2) {
            const int c_ = k2 * 16 + cpart;
            uint2 x = *(const uint2*)&T[c_ * 132 + m * 8];
            uint2 y = *(const uint2*)&T[c_ * 132 + m * 8 + 4];
            uint4 w; w.x = x.x; w.y = x.y; w.z = y.x; w.w = y.y;
            *(uint4*)&op.OutT[(size_t)(bn * BN + c_) * ldo + bm * BM + m * 8] = w;
        }
    }
}

static inline GemmOp mkop(const u16* U, const u16* V, int K, int ldu, int ldv,
                          const float* Add, u16* OutB, u16* OutT, float* OutF,
                          int N = 2048, int ldo = 2048) {
    GemmOp o;
    o.U = U; o.V = V; o.Add = Add; o.OutB = OutB; o.OutT = OutT; o.OutF = OutF;
    o.K = K; o.ldu = ldu; o.ldv = ldv; o.N = N; o.ldo = ldo;
    return o;
}

extern "C" void kernel_launch(void* const* d_in, const int* in_sizes, int n_in,
                              void* d_out, int out_size, void* d_ws, size_t ws_size,
                              hipStream_t stream) {
    const float* A = (const float*)d_in[0];     // (2048, 2048)
    const float* A_F = (const float*)d_in[1];   // (2048, 2048)
    const float* C = (const float*)d_in[2];     // (512, 2048)
    const float* C_F = (const float*)d_in[3];   // (512, 2048)
    const int n = 2048, p = 512;
    (void)in_sizes; (void)n_in; (void)out_size; (void)ws_size;

    char* ws = (char*)d_ws;
    const size_t MB = 1u << 20;
    // ---- Smith squaring, 5 levels -> S_32 (tail bound: see R12 notes;
    // absmax 0.5 measured, threshold 2.33).
    // R17 d0b-fold: R_1 = [CFT|W1] [CT|Y]^T in ONE K=1024 GEMM (kills the
    // separate R0 op + its 16 MB write + 16 MB Add read; fp32 acc over the
    // whole K — numerics same or better).
    u16* AT   = (u16*)(ws + 0 * MB);    // A^T  bf16  (A_0 transposed form)
    u16* Ab   = (u16*)(ws + 8 * MB);    // A    bf16  (A_0 row form)
    u16* AFT  = (u16*)(ws + 16 * MB);   // B=A_F^T row bf16 (B_0 row form)
    u16* AFb  = (u16*)(ws + 24 * MB);   // A_F  bf16  (B_0 transposed form)
    u16* WYU  = (u16*)(ws + 32 * MB);   // 2048x1024: [CFT | W1=B C_F^T]
    u16* WYV  = (u16*)(ws + 36 * MB);   // 2048x1024: [CT  | Y=A^T C^T]
    u16* XT   = (u16*)(ws + 32 * MB);   // (R A_i)^T — overlaps WYU/WYV (dead after d0b)
    float* R32 = (float*)(ws + 40 * MB);// running R fp32
    u16* Rb   = (u16*)(ws + 56 * MB);   // running R bf16 row
    u16* CFb  = (u16*)(ws + 64 * MB);   // C_F bf16 row (level 0 only)
    u16* Cb   = (u16*)(ws + 66 * MB);   // C   bf16 row (level 0 only)
    u16* Tb1  = (u16*)(ws + 68 * MB);   // ping-pong set 1: B_i row
    u16* TbT1 = (u16*)(ws + 76 * MB);   //                  B_i^T
    u16* Ub1  = (u16*)(ws + 84 * MB);   //                  A_i row
    u16* UbT1 = (u16*)(ws + 92 * MB);   //                  A_i^T   (top = 100 MB)

    dim3 tb(32, 8);
    stein_prep_sq<<<dim3(64, 64), tb, 0, stream>>>(A, Ab, AT, n);
    stein_prep_sq<<<dim3(64, 64), tb, 0, stream>>>(A_F, AFb, AFT, n);
    stein_prep_rect<<<dim3(64, 16), tb, 0, stream>>>(C_F, CFb, WYU, p, n, 2 * p);
    stein_prep_rect<<<dim3(64, 16), tb, 0, stream>>>(C, Cb, WYV, p, n, 2 * p);

    u16* Tb[2]  = {AFT, Tb1};
    u16* TbT[2] = {AFb, TbT1};
    u16* Ub[2]  = {Ab, Ub1};
    u16* UbT[2] = {AT, UbT1};

    dim3 blk(256);
    dim3 g1(16, 16, 1), g2(16, 16, 2), g4(16, 16, 4);

    // d0 (z=4): level-0 independent ops. Long K=2048 small-N ops at LOW z
    // (dispatched first) so stragglers are short.
    {
        GemmOp oW1  = mkop(AFT, CFb, n, n, n, nullptr, WYU + p, nullptr, nullptr, p, 2 * p);
        GemmOp oY   = mkop(AT, Cb, n, n, n, nullptr, WYV + p, nullptr, nullptr, p, 2 * p);
        GemmOp oAsq = mkop(Ub[0], UbT[0], n, n, n, nullptr, Ub[1], UbT[1], nullptr);
        GemmOp oBsq = mkop(Tb[0], TbT[0], n, n, n, nullptr, Tb[1], TbT[1], nullptr);
        stein_gemm_nt2<<<g4, blk, 0, stream>>>(oW1, oY, oAsq, oBsq, oBsq);
    }
    // d0b: R_1 = [CFT|W1] [CT|Y]^T  (K=1024 concat = RHS + B RHS A)
    {
        GemmOp oR1 = mkop(WYU, WYV, 2 * p, 2 * p, 2 * p, nullptr, Rb, nullptr, R32);
        stein_gemm_nt2<<<g1, blk, 0, stream>>>(oR1, oR1, oR1, oR1, oR1);
    }

    // levels 1..3: full doubling, stream-sharing pairing.
    // R_j = S_{2^j}; after level 3: R_4 = S_16, A_4 = A^16 in set 0.
    // Level 3 drops dead outputs (level 4 needs only UbT[0] and Tb[0]).
    for (int i = 1; i < 4; ++i) {
        const int c = i & 1, nx = c ^ 1;
        GemmOp oXT = mkop(Rb, UbT[c], n, n, n, nullptr, nullptr, XT, nullptr);
        // d1: {XT = R A_i, Asq = A_i^2} — shared V stream = A_i^T.
        GemmOp oAsq = mkop(Ub[c], UbT[c], n, n, n, nullptr,
                           (i == 3) ? nullptr : Ub[nx], UbT[nx], nullptr);
        stein_gemm_nt2<<<g2, blk, 0, stream>>>(oXT, oAsq, oAsq, oAsq, oAsq);
        // d2: {Rup = B_i X + R, Bsq = B_i^2} — shared U stream = B_i.
        GemmOp oRup = mkop(Tb[c], XT, n, n, n, R32, Rb, nullptr, R32);
        GemmOp oBsq = mkop(Tb[c], TbT[c], n, n, n, nullptr, Tb[nx],
                           (i == 3) ? nullptr : TbT[nx], nullptr);
        stein_gemm_nt2<<<g2, blk, 0, stream>>>(oRup, oBsq, oBsq, oBsq, oBsq);
    }

    // level 4 (final): S_32 = R_4 + B_4 (R_4 A_4) -> d_out. A_4/B_4 in set 0.
    {
        const int c = 0;
        GemmOp oXT = mkop(Rb, UbT[c], n, n, n, nullptr, nullptr, XT, nullptr);
        stein_gemm_nt2<<<g1, blk, 0, stream>>>(oXT, oXT, oXT, oXT, oXT);
        GemmOp oFin = mkop(Tb[c], XT, n, n, n, R32, nullptr, nullptr, (float*)d_out);
        stein_gemm_nt2<<<g1, blk, 0, stream>>>(oFin, oFin, oFin, oFin, oFin);
    }
}